// Round 7
// baseline (334.853 us; speedup 1.0000x reference)
//
#include <hip/hip_runtime.h>

// ---------------------------------------------------------------------------
// LuminanceAwareMHSA: B=4, C=256, H=W=48 (N=2304), HEADS=8, DH=32, HID=128
// Round 7: k6 LDS round-trip eliminated via K=16 PV MFMA: the 16x16 D-layout
// (row=(lane>>4)*4+reg, col=lane&15) is IDENTICAL to the 16x16x16 B-layout
// (k=(lane>>4)*4+j, n=lane&15), so exp2'd S^T rows pack directly into the PV
// B-fragment. No LDS, no bank conflicts, short dependency chains.
// Also: k1 rewritten with wave-shfl reductions (3 barriers, was ~20);
// k4 GEMV reads made coalesced (was stride-512B per lane).
//   k0b  cast all weights to bf16;  k0xt transpose x -> xt[b][n][c] bf16
//   K1   luma + min/max norm + pooled-invL bias (pre-scaled alpha*log2e)
//   K2   conv1 3x3 (1->128) + relu -> bf16 padded h1p
//   K3   conv2 via mfma + relu + column-sum -> hm_sum atomics
//   K4   FiLM params (coalesced GEMV)
//   K5   QKV via MFMA + FiLM epilogue -> bf16 q_t/k_t [B,H,N,32], v [B,256,N]
//   K6   flash attention (split-K=2, LDS-free) -> bf16 O partials [B,N,256]
//   K7   projection via MFMA, split-combine through MFMA C chain -> d_out
// ---------------------------------------------------------------------------

#define NSP 2304
#define WID 48

typedef __attribute__((ext_vector_type(4))) float  fvec4;
typedef __attribute__((ext_vector_type(2))) unsigned int uvec2;
typedef __attribute__((ext_vector_type(4))) unsigned int uvec4;
typedef __attribute__((ext_vector_type(8))) short  short8;   // 8 bf16 (4 VGPRs)
typedef __attribute__((ext_vector_type(4))) short  sh4;      // 4 bf16 (2 VGPRs)
typedef __attribute__((ext_vector_type(4))) float  f32x4;    // MFMA C/D

#if __has_builtin(__builtin_amdgcn_mfma_f32_16x16x16_bf16)
#define MFMA16(A,B,C) __builtin_amdgcn_mfma_f32_16x16x16_bf16(A,B,C,0,0,0)
#define HAVE_MFMA16 1
#elif __has_builtin(__builtin_amdgcn_mfma_f32_16x16x16bf16_1k)
#define MFMA16(A,B,C) __builtin_amdgcn_mfma_f32_16x16x16bf16_1k(A,B,C,0,0,0)
#define HAVE_MFMA16 1
#else
#define HAVE_MFMA16 0
#endif

__device__ inline unsigned short f2bf(float f){
  unsigned int u = __builtin_bit_cast(unsigned int, f);
  u += 0x7fffu + ((u >> 16) & 1u);           // RNE
  return (unsigned short)(u >> 16);
}
__device__ inline unsigned pack2bf(float a, float b){
#if __has_builtin(__builtin_amdgcn_cvt_pk_bf16_f32)
  typedef __attribute__((ext_vector_type(2))) __bf16 bf16x2;
  bf16x2 r = __builtin_amdgcn_cvt_pk_bf16_f32(a, b);
  return __builtin_bit_cast(unsigned, r);
#else
  return (unsigned)f2bf(a) | ((unsigned)f2bf(b) << 16);
#endif
}

// ---------------------------------------------------------------------------
// k0b: cast weights to bf16. idx ranges: [0,147456) wtb, [..,344064) wqkvb,
// [..,409600) wprojb. grid 1600 x 256.
__global__ void k0b_wcast(const float* __restrict__ c2w, const float* __restrict__ wq,
                          const float* __restrict__ wk, const float* __restrict__ wv_,
                          const float* __restrict__ wproj,
                          unsigned short* __restrict__ wtb,
                          unsigned short* __restrict__ wqkvb,
                          unsigned short* __restrict__ wprojb){
  int idx = blockIdx.x*256 + threadIdx.x;
  if (idx < 147456){
    int ic = idx & 127, rem = idx >> 7;
    int oc = rem & 127, tap = rem >> 7;
    wtb[idx] = f2bf(c2w[(oc*128 + ic)*9 + tap]);
  } else if (idx < 344064){
    int j = idx - 147456;
    int mat = j >> 16, oc_ = j & 65535;
    const float* src = (mat == 0) ? wq : (mat == 1) ? wk : wv_;
    wqkvb[j] = f2bf(src[oc_]);
  } else {
    int j = idx - 344064;
    wprojb[j] = f2bf(wproj[j]);
  }
}

// ---------------------------------------------------------------------------
// k0xt: xt[b][n][c] = bf16(x[b][c][n]). grid (36 nt, 4 cc, 4 b), 64n x 64c tile.
__global__ __launch_bounds__(256) void k0xt(const float* __restrict__ x,
                                            unsigned short* __restrict__ xt){
  int nt = blockIdx.x, cc = blockIdx.y, b = blockIdx.z, t = threadIdx.x;
  __shared__ unsigned short tb[64*72];
  int cl0 = t >> 4;           // 0..15
  int nl0 = (t & 15) * 4;     // 0..60
  #pragma unroll
  for (int ps = 0; ps < 4; ++ps){
    int cl = cl0 + ps*16;
    fvec4 v = *(const fvec4*)(x + ((size_t)(b*256 + cc*64 + cl))*NSP + nt*64 + nl0);
    #pragma unroll
    for (int i = 0; i < 4; ++i) tb[(nl0+i)*72 + cl] = f2bf(v[i]);
  }
  __syncthreads();
  int nl = t >> 2, cg = (t & 3) * 16;
  uvec4 u0 = *(const uvec4*)&tb[nl*72 + cg];
  uvec4 u1 = *(const uvec4*)&tb[nl*72 + cg + 8];
  unsigned short* dst = xt + ((size_t)(b*NSP + nt*64 + nl))*256 + cc*64 + cg;
  *(uvec4*)dst = u0;
  *(uvec4*)(dst + 8) = u1;
}

// ---------------------------------------------------------------------------
// K1: luma -> minmax-normalize; 3x3 zero-pad avg-pool of (1-luma); mean-center
//     and pre-multiply by alpha*log2e. Wave-shfl reductions, 3 barriers.
__global__ void k1_luma(const float* __restrict__ rgb, const float* __restrict__ alphaP,
                        float* __restrict__ luma_n, float* __restrict__ bias_a,
                        float* __restrict__ hm_sum){
  int b = blockIdx.x, t = threadIdx.x;
  int wv = t >> 6, lane = t & 63;
  __shared__ float ll[NSP];
  __shared__ float red[8];
  const float* rp = rgb + b*3*NSP;
  float ly[9];
  float lmin = 1e30f, lmax = -1e30f;
  #pragma unroll
  for (int ii = 0; ii < 9; ++ii){
    int i = t + 256*ii;
    float y = 0.299f*rp[i] + 0.587f*rp[NSP+i] + 0.114f*rp[2*NSP+i];
    ly[ii] = y; lmin = fminf(lmin, y); lmax = fmaxf(lmax, y);
  }
  #pragma unroll
  for (int o2 = 1; o2 < 64; o2 <<= 1){
    lmin = fminf(lmin, __shfl_xor(lmin, o2, 64));
    lmax = fmaxf(lmax, __shfl_xor(lmax, o2, 64));
  }
  if (lane == 0){ red[wv] = lmin; red[4+wv] = lmax; }
  if (t < 128) hm_sum[b*128 + t] = 0.f;
  __syncthreads();
  float mn = fminf(fminf(red[0], red[1]), fminf(red[2], red[3]));
  float mx = fmaxf(fmaxf(red[4], red[5]), fmaxf(red[6], red[7]));
  float inv = 1.0f / (mx - mn + 1e-6f);
  #pragma unroll
  for (int ii = 0; ii < 9; ++ii){
    int i = t + 256*ii;
    float v = (ly[ii] - mn) * inv;
    ll[i] = v;
    luma_n[b*NSP + i] = v;
  }
  __syncthreads();
  float pr[9]; float psum = 0.f;
  #pragma unroll
  for (int ii = 0; ii < 9; ++ii){
    int n = t + 256*ii;
    int row = n / WID, col = n - row*WID;
    float s = 0.f;
    #pragma unroll
    for (int dy = -1; dy <= 1; ++dy)
      #pragma unroll
      for (int dx = -1; dx <= 1; ++dx){
        int r2 = row+dy, c2 = col+dx;
        if (r2 >= 0 && r2 < WID && c2 >= 0 && c2 < WID) s += 1.0f - ll[r2*WID + c2];
      }
    pr[ii] = s * (1.f/9.f);
    psum += pr[ii];
  }
  #pragma unroll
  for (int o2 = 1; o2 < 64; o2 <<= 1) psum += __shfl_xor(psum, o2, 64);
  if (lane == 0) red[wv] = psum;
  __syncthreads();
  float mean = (red[0] + red[1] + red[2] + red[3]) * (1.f/(float)NSP);
  float alpha = alphaP[0] * 1.4426950408889634f;   // fold log2(e) for exp2
  #pragma unroll
  for (int ii = 0; ii < 9; ++ii){
    int n = t + 256*ii;
    bias_a[b*NSP + n] = alpha * (pr[ii] - mean);
  }
}

// ---------------------------------------------------------------------------
// K2: conv1 3x3, 1 -> 128 channels, relu -> bf16 padded h1p[b][50*50][128].
__global__ void k2_conv1(const float* __restrict__ luma_n, const float* __restrict__ c1w,
                         const float* __restrict__ c1b, unsigned short* __restrict__ h1p){
  int nt = blockIdx.x, ocg = blockIdx.y, b = blockIdx.z, t = threadIdx.x;
  __shared__ float wsm[32*9];
  __shared__ float bsm[32];
  for (int i = t; i < 288; i += 256) wsm[i] = c1w[ocg*288 + i];
  if (t < 32) bsm[t] = c1b[ocg*32 + t];
  __syncthreads();
  int n = nt*256 + t;
  int row = n / WID, col = n - row*WID;
  const float* lp = luma_n + b*NSP;
  float lv[9];
  int k = 0;
  #pragma unroll
  for (int dy = -1; dy <= 1; ++dy)
    #pragma unroll
    for (int dx = -1; dx <= 1; ++dx, ++k){
      int r2 = row+dy, c2 = col+dx;
      lv[k] = (r2 >= 0 && r2 < WID && c2 >= 0 && c2 < WID) ? lp[r2*WID + c2] : 0.f;
    }
  unsigned int packed[16];
  #pragma unroll
  for (int oc2 = 0; oc2 < 16; ++oc2){
    float a0 = bsm[oc2*2], a1 = bsm[oc2*2+1];
    #pragma unroll
    for (int q = 0; q < 9; ++q){
      a0 += wsm[(oc2*2)*9 + q] * lv[q];
      a1 += wsm[(oc2*2+1)*9 + q] * lv[q];
    }
    packed[oc2] = pack2bf(fmaxf(a0, 0.f), fmaxf(a1, 0.f));
  }
  unsigned short* dst = h1p + ((size_t)(b*2500 + (row+1)*50 + (col+1)))*128 + ocg*32;
  #pragma unroll
  for (int q4 = 0; q4 < 4; ++q4)
    *(uvec4*)(dst + q4*8) = *(uvec4*)&packed[q4*4];
}

// ---------------------------------------------------------------------------
// K3: conv2 128->128 as 9 shifted MFMA GEMMs + relu + column-sum -> hm_sum.
__global__ __launch_bounds__(256) void k3_conv2(const unsigned short* __restrict__ h1p,
    const unsigned short* __restrict__ wtb, const float* __restrict__ c2b,
    float* __restrict__ hm_sum){
  int row = blockIdx.x, mh = blockIdx.y, b = blockIdx.z;
  int t = threadIdx.x, wv = t >> 6, lane = t & 63;
  int lq = lane >> 4, lc = lane & 15;
  int ocb = mh*64 + wv*16;
  const f32x4 z4 = {0.f, 0.f, 0.f, 0.f};
  f32x4 C[3] = {z4, z4, z4};
  const unsigned short* hbase = h1p + (size_t)b*2500*128;
  #pragma unroll
  for (int tap = 0; tap < 9; ++tap){
    int dy = tap/3 - 1, dx = tap%3 - 1;
    const unsigned short* wrow = wtb + (tap*128 + ocb + lc)*128 + lq*8;
    const unsigned short* hrow = hbase + ((row+dy+1)*50 + (dx+1) + lc)*128 + lq*8;
    #pragma unroll
    for (int kc = 0; kc < 4; ++kc){
      short8 aW = *(const short8*)(wrow + kc*32);
      #pragma unroll
      for (int ntp = 0; ntp < 3; ++ntp){
        short8 bH = *(const short8*)(hrow + ntp*16*128 + kc*32);
        C[ntp] = __builtin_amdgcn_mfma_f32_16x16x32_bf16(aW, bH, C[ntp], 0, 0, 0);
      }
    }
  }
  float s[4];
  #pragma unroll
  for (int r = 0; r < 4; ++r){
    float bias = c2b[ocb + lq*4 + r];
    float v = 0.f;
    #pragma unroll
    for (int ntp = 0; ntp < 3; ++ntp) v += fmaxf(C[ntp][r] + bias, 0.f);
    v += __shfl_xor(v, 1, 64);
    v += __shfl_xor(v, 2, 64);
    v += __shfl_xor(v, 4, 64);
    v += __shfl_xor(v, 8, 64);
    s[r] = v;
  }
  if (lc == 0){
    #pragma unroll
    for (int r = 0; r < 4; ++r)
      atomicAdd(&hm_sum[b*128 + ocb + lq*4 + r], s[r]);
  }
}

// ---------------------------------------------------------------------------
// K4: FiLM params, coalesced GEMV. film[(m6*4+b)*256 + o].
// 256 threads = 32 o-lanes x 8 h-groups (16 h each); 8 passes; shfl-reduce.
__global__ void k4_film(const float* __restrict__ hm_sum,
  const float* w0, const float* b0, const float* w1, const float* b1,
  const float* w2, const float* b2, const float* w3, const float* b3,
  const float* w4, const float* b4, const float* w5, const float* b5,
  float* __restrict__ film){
  __shared__ float hs[128];
  int bb = blockIdx.x & 3, m6 = blockIdx.x >> 2, t = threadIdx.x;
  if (t < 128) hs[t] = hm_sum[bb*128 + t] * (1.f/(float)NSP);
  __syncthreads();
  const float* wm[6] = {w0,w1,w2,w3,w4,w5};
  const float* bm[6] = {b0,b1,b2,b3,b4,b5};
  const float* w = wm[m6];
  const float* bv6 = bm[m6];
  int oi = t >> 3, hi = t & 7;
  float hreg[16];
  #pragma unroll
  for (int q = 0; q < 16; ++q) hreg[q] = hs[hi*16 + q];
  #pragma unroll
  for (int pass = 0; pass < 8; ++pass){
    int o = pass*32 + oi;
    const float* wr = w + o*128 + hi*16;
    float p = 0.f;
    #pragma unroll
    for (int q4 = 0; q4 < 4; ++q4){
      fvec4 w4v = *(const fvec4*)(wr + q4*4);
      p += hreg[q4*4+0]*w4v[0] + hreg[q4*4+1]*w4v[1]
         + hreg[q4*4+2]*w4v[2] + hreg[q4*4+3]*w4v[3];
    }
    p += __shfl_xor(p, 1, 64);
    p += __shfl_xor(p, 2, 64);
    p += __shfl_xor(p, 4, 64);
    if (hi == 0) film[blockIdx.x*256 + o] = p + bv6[o];
  }
}

// ---------------------------------------------------------------------------
// K5: QKV via bf16 MFMA. grid (36 nt, 6 ot, 4 b); FiLM epilogue; emits
// q_t/k_t [B,8,N,32] bf16 (SCALE*log2e in q), v_b [B,256,N] bf16.
__global__ __launch_bounds__(256) void k5_qkv(const unsigned short* __restrict__ xt,
    const unsigned short* __restrict__ wqkvb,
    const float* __restrict__ bq, const float* __restrict__ bk, const float* __restrict__ bv,
    const float* __restrict__ film,
    unsigned short* __restrict__ q_t, unsigned short* __restrict__ k_t,
    unsigned short* __restrict__ v_b){
  int nt = blockIdx.x, ot = blockIdx.y, b = blockIdx.z;
  int t = threadIdx.x, wv = t >> 6, lane = t & 63;
  int lq = lane >> 4, lc = lane & 15;
  int p = ot >> 1;
  int omb = (ot & 1)*128 + wv*32;
  const unsigned short* wb = wqkvb + p*65536;
  const f32x4 z4 = {0.f, 0.f, 0.f, 0.f};
  f32x4 acc[2][4];
  #pragma unroll
  for (int oh = 0; oh < 2; ++oh)
    #pragma unroll
    for (int nq = 0; nq < 4; ++nq) acc[oh][nq] = z4;
  for (int kc = 0; kc < 8; ++kc){
    short8 aW[2];
    #pragma unroll
    for (int oh = 0; oh < 2; ++oh)
      aW[oh] = *(const short8*)(wb + (omb + oh*16 + lc)*256 + kc*32 + lq*8);
    short8 bX[4];
    #pragma unroll
    for (int nq = 0; nq < 4; ++nq)
      bX[nq] = *(const short8*)(xt + ((size_t)(b*NSP + nt*64 + nq*16 + lc))*256 + kc*32 + lq*8);
    #pragma unroll
    for (int oh = 0; oh < 2; ++oh)
      #pragma unroll
      for (int nq = 0; nq < 4; ++nq)
        acc[oh][nq] = __builtin_amdgcn_mfma_f32_16x16x32_bf16(aW[oh], bX[nq], acc[oh][nq], 0, 0, 0);
  }
  const float* bvec = (p == 0) ? bq : (p == 1) ? bk : bv;
  int hq = omb >> 5;
  unsigned short* qk = (p == 0) ? q_t : k_t;
  #pragma unroll
  for (int oh = 0; oh < 2; ++oh){
    fvec4 g4 = *(const fvec4*)(film + (2*p*4 + b)*256 + omb + oh*16 + lq*4);
    fvec4 t4 = *(const fvec4*)(film + ((2*p+1)*4 + b)*256 + omb + oh*16 + lq*4);
    fvec4 z4b = *(const fvec4*)(bvec + omb + oh*16 + lq*4);
    #pragma unroll
    for (int nq = 0; nq < 4; ++nq){
      int n = nt*64 + nq*16 + lc;
      float v0 = g4[0]*(acc[oh][nq][0] + z4b[0]) + t4[0];
      float v1 = g4[1]*(acc[oh][nq][1] + z4b[1]) + t4[1];
      float v2 = g4[2]*(acc[oh][nq][2] + z4b[2]) + t4[2];
      float v3 = g4[3]*(acc[oh][nq][3] + z4b[3]) + t4[3];
      if (p == 0){
        const float sc = 0.17677669529663687f * 1.4426950408889634f;  // SCALE*log2e
        v0 *= sc; v1 *= sc; v2 *= sc; v3 *= sc;
      }
      if (p < 2){
        uvec2 u;
        u.x = pack2bf(v0, v1);
        u.y = pack2bf(v2, v3);
        *(uvec2*)(qk + ((size_t)((b*8 + hq)*NSP + n))*32 + oh*16 + lq*4) = u;
      } else {
        int om = omb + oh*16 + lq*4;
        v_b[((size_t)(b*256 + om + 0))*NSP + n] = f2bf(v0);
        v_b[((size_t)(b*256 + om + 1))*NSP + n] = f2bf(v1);
        v_b[((size_t)(b*256 + om + 2))*NSP + n] = f2bf(v2);
        v_b[((size_t)(b*256 + om + 3))*NSP + n] = f2bf(v3);
      }
    }
  }
}

// ---------------------------------------------------------------------------
// K6: flash attention, split-K=2. Per wave: 32 queries, 64-key tiles.
// S^T = mfma_16x16x32(A=K, B=Q^T, C=bias): D[key=lq*4+r][query=lc].
// PV via K=16 MFMA: packed exp2(S^T) rows ARE the B-fragment (D-layout ==
// 16x16x16 B-layout). l = sum_keys P via ones-MFMA. bf16 O partials in
// [B,N,256] (k7 B-frag layout) + f32 l. grid (36 = 18 qblk x 2 split, 8 h, 4 b).
__global__ __launch_bounds__(256) void k6_attn(const unsigned short* __restrict__ q_t,
    const unsigned short* __restrict__ k_t, const unsigned short* __restrict__ v_b,
    const float* __restrict__ bias_a,
    unsigned short* __restrict__ o0, unsigned short* __restrict__ o1,
    float* __restrict__ l0, float* __restrict__ l1){
  int bx = blockIdx.x, h = blockIdx.y, b = blockIdx.z;
  int qblk = bx >> 1, s = bx & 1;
  unsigned short* op = s ? o1 : o0;
  float* lp = s ? l1 : l0;
  int t = threadIdx.x, wv = t >> 6, lane = t & 63;
  int lq = lane >> 4, lc = lane & 15;
  int bh = b*8 + h;
  int nb0 = qblk*128 + wv*32;
  const f32x4 z4 = {0.f, 0.f, 0.f, 0.f};
  short8 aQ[2];
  #pragma unroll
  for (int qf = 0; qf < 2; ++qf)
    aQ[qf] = *(const short8*)(q_t + ((size_t)(bh*NSP + nb0 + qf*16 + lc))*32 + lq*8);
  f32x4 O[2][2];
  f32x4 Ol[2];
  #pragma unroll
  for (int qf = 0; qf < 2; ++qf){
    Ol[qf] = z4;
    #pragma unroll
    for (int dh = 0; dh < 2; ++dh) O[qf][dh] = z4;
  }
  const float* brow = bias_a + b*NSP;
  int ms = s*1152;

#if HAVE_MFMA16
  const uvec2 ones2 = {0x3F803F80u, 0x3F803F80u};
  const sh4 aOnes16 = __builtin_bit_cast(sh4, ones2);
  for (int it = 0; it < 18; ++it){
    int m0 = ms + it*64;
    short8 aK[4]; fvec4 c0[4]; sh4 aV16[2][4];
    #pragma unroll
    for (int g = 0; g < 4; ++g)
      aK[g] = *(const short8*)(k_t + ((size_t)(bh*NSP + m0 + g*16 + lc))*32 + lq*8);
    #pragma unroll
    for (int g = 0; g < 4; ++g)
      c0[g] = *(const fvec4*)(brow + m0 + g*16 + lq*4);
    #pragma unroll
    for (int dh = 0; dh < 2; ++dh)
      #pragma unroll
      for (int g = 0; g < 4; ++g)
        aV16[dh][g] = *(const sh4*)(v_b + ((size_t)(b*256 + h*32 + dh*16 + lc))*NSP + m0 + g*16 + lq*4);
    #pragma unroll
    for (int qf = 0; qf < 2; ++qf){
      #pragma unroll
      for (int g = 0; g < 4; ++g){
        f32x4 S = __builtin_amdgcn_mfma_f32_16x16x32_bf16(aK[g], aQ[qf], c0[g], 0, 0, 0);
        uvec2 w2;
        w2.x = pack2bf(__builtin_amdgcn_exp2f(S[0]), __builtin_amdgcn_exp2f(S[1]));
        w2.y = pack2bf(__builtin_amdgcn_exp2f(S[2]), __builtin_amdgcn_exp2f(S[3]));
        sh4 bP = __builtin_bit_cast(sh4, w2);
        Ol[qf] = MFMA16(aOnes16, bP, Ol[qf]);
        O[qf][0] = MFMA16(aV16[0][g], bP, O[qf][0]);
        O[qf][1] = MFMA16(aV16[1][g], bP, O[qf][1]);
      }
    }
  }
#else
  // fallback: per-wave LDS scratch (round-6 path)
  __shared__ float ps[4][512];
  float* myps = ps[wv];
  int xm = (lc & 7) << 2;
  int wbase = lc*32;
  const uvec4 onesu = {0x3F803F80u, 0x3F803F80u, 0x3F803F80u, 0x3F803F80u};
  const short8 aOnes = __builtin_bit_cast(short8, onesu);
  for (int it = 0; it < 18; ++it){
    int m0 = ms + it*64;
    short8 aK[4]; fvec4 c0[4]; short8 aV[2][2];
    #pragma unroll
    for (int g = 0; g < 4; ++g)
      aK[g] = *(const short8*)(k_t + ((size_t)(bh*NSP + m0 + g*16 + lc))*32 + lq*8);
    #pragma unroll
    for (int g = 0; g < 4; ++g)
      c0[g] = *(const fvec4*)(brow + m0 + g*16 + lq*4);
    #pragma unroll
    for (int dh = 0; dh < 2; ++dh)
      #pragma unroll
      for (int mh = 0; mh < 2; ++mh)
        aV[dh][mh] = *(const short8*)(v_b + ((size_t)(b*256 + h*32 + dh*16 + lc))*NSP + m0 + mh*32 + lq*8);
    #pragma unroll
    for (int qf = 0; qf < 2; ++qf){
      #pragma unroll
      for (int g = 0; g < 4; ++g){
        f32x4 S = __builtin_amdgcn_mfma_f32_16x16x32_bf16(aK[g], aQ[qf], c0[g], 0, 0, 0);
        uvec2 w2;
        w2.x = pack2bf(__builtin_amdgcn_exp2f(S[0]), __builtin_amdgcn_exp2f(S[1]));
        w2.y = pack2bf(__builtin_amdgcn_exp2f(S[2]), __builtin_amdgcn_exp2f(S[3]));
        int kp = g*8 + lq*2;
        *(uvec2*)&myps[wbase + (kp ^ xm)] = w2;
      }
      #pragma unroll
      for (int mh = 0; mh < 2; ++mh){
        int rb = (mh*16 + lq*4) ^ xm;
        uvec4 up = *(const uvec4*)&myps[wbase + rb];
        short8 bP = __builtin_bit_cast(short8, up);
        Ol[qf] = __builtin_amdgcn_mfma_f32_16x16x32_bf16(aOnes, bP, Ol[qf], 0, 0, 0);
        #pragma unroll
        for (int dh = 0; dh < 2; ++dh)
          O[qf][dh] = __builtin_amdgcn_mfma_f32_16x16x32_bf16(aV[dh][mh], bP, O[qf][dh], 0, 0, 0);
      }
    }
  }
#endif
  // store bf16 O partials [b][n][og] (og = h*32 + d), f32 l partials
  #pragma unroll
  for (int qf = 0; qf < 2; ++qf){
    int nidx = nb0 + qf*16 + lc;
    if (lq == 0) lp[b*NSP + nidx] = Ol[qf][0];
    #pragma unroll
    for (int dh = 0; dh < 2; ++dh){
      uvec2 u;
      u.x = pack2bf(O[qf][dh][0], O[qf][dh][1]);
      u.y = pack2bf(O[qf][dh][2], O[qf][dh][3]);
      *(uvec2*)(op + ((size_t)(b*NSP + nidx))*256 + h*32 + dh*16 + lq*4) = u;
    }
  }
}

// ---------------------------------------------------------------------------
// K7: out[c][n] = (sum_o wproj[c][o]*(a0+a1)[o][n]) * rl[n] + bproj[c].
// bf16 MFMA; a0/a1 combined through the MFMA C chain. grid (72,2,4).
__global__ __launch_bounds__(256) void k7_proj(const unsigned short* __restrict__ a0,
    const unsigned short* __restrict__ a1, const float* __restrict__ l0p,
    const float* __restrict__ l1p, const unsigned short* __restrict__ wprojb,
    const float* __restrict__ bproj, float* __restrict__ out){
  int nt = blockIdx.x, ct = blockIdx.y, b = blockIdx.z;
  int t = threadIdx.x, wv = t >> 6, lane = t & 63;
  int lq = lane >> 4, lc = lane & 15;
  __shared__ float rls[32];
  if (t < 32) rls[t] = 1.0f / (l0p[b*NSP + nt*32 + t] + l1p[b*NSP + nt*32 + t]);
  __syncthreads();
  int cb = ct*128 + wv*32;
  const f32x4 z4 = {0.f, 0.f, 0.f, 0.f};
  f32x4 acc[2][2];
  #pragma unroll
  for (int ch = 0; ch < 2; ++ch)
    #pragma unroll
    for (int nq = 0; nq < 2; ++nq) acc[ch][nq] = z4;
  for (int kc = 0; kc < 8; ++kc){
    short8 aW[2];
    #pragma unroll
    for (int ch = 0; ch < 2; ++ch)
      aW[ch] = *(const short8*)(wprojb + (cb + ch*16 + lc)*256 + kc*32 + lq*8);
    #pragma unroll
    for (int src = 0; src < 2; ++src){
      const unsigned short* ap = src ? a1 : a0;
      short8 bA[2];
      #pragma unroll
      for (int nq = 0; nq < 2; ++nq)
        bA[nq] = *(const short8*)(ap + ((size_t)(b*NSP + nt*32 + nq*16 + lc))*256 + kc*32 + lq*8);
      #pragma unroll
      for (int ch = 0; ch < 2; ++ch)
        #pragma unroll
        for (int nq = 0; nq < 2; ++nq)
          acc[ch][nq] = __builtin_amdgcn_mfma_f32_16x16x32_bf16(aW[ch], bA[nq], acc[ch][nq], 0, 0, 0);
    }
  }
  #pragma unroll
  for (int ch = 0; ch < 2; ++ch){
    #pragma unroll
    for (int nq = 0; nq < 2; ++nq){
      int n = nt*32 + nq*16 + lc;
      float rl = rls[nq*16 + lc];
      #pragma unroll
      for (int r = 0; r < 4; ++r){
        int c = cb + ch*16 + lq*4 + r;
        out[((size_t)(b*256 + c))*NSP + n] = acc[ch][nq][r]*rl + bproj[c];
      }
    }
  }
}

// ---------------------------------------------------------------------------
extern "C" void kernel_launch(void* const* d_in, const int* in_sizes, int n_in,
                              void* d_out, int out_size, void* d_ws, size_t ws_size,
                              hipStream_t stream) {
  const float* x     = (const float*)d_in[0];
  const float* rgb   = (const float*)d_in[1];
  const float* wq    = (const float*)d_in[2];
  const float* bq    = (const float*)d_in[3];
  const float* wk    = (const float*)d_in[4];
  const float* bk    = (const float*)d_in[5];
  const float* wv    = (const float*)d_in[6];
  const float* bv    = (const float*)d_in[7];
  const float* wproj = (const float*)d_in[8];
  const float* bproj = (const float*)d_in[9];
  const float* c1w   = (const float*)d_in[10];
  const float* c1b   = (const float*)d_in[11];
  const float* c2w   = (const float*)d_in[12];
  const float* c2b   = (const float*)d_in[13];
  const float* gq_w  = (const float*)d_in[14];
  const float* gq_b  = (const float*)d_in[15];
  const float* bqf_w = (const float*)d_in[16];
  const float* bqf_b = (const float*)d_in[17];
  const float* gk_w  = (const float*)d_in[18];
  const float* gk_b  = (const float*)d_in[19];
  const float* bkf_w = (const float*)d_in[20];
  const float* bkf_b = (const float*)d_in[21];
  const float* gv_w  = (const float*)d_in[22];
  const float* gv_b  = (const float*)d_in[23];
  const float* bvf_w = (const float*)d_in[24];
  const float* bvf_b = (const float*)d_in[25];
  const float* alphaP= (const float*)d_in[26];

  char* w = (char*)d_ws;
  float* luma_n = (float*)w;            w += 4*NSP*4;
  float* bias_a = (float*)w;            w += 4*NSP*4;
  float* hm_sum = (float*)w;            w += 512*4;
  float* film   = (float*)w;            w += 6*4*256*4;
  unsigned short* h1p = (unsigned short*)w; w += 4*2500*128*2;
  unsigned short* wtb = (unsigned short*)w; w += 9*128*128*2;
  unsigned short* wqkvb = (unsigned short*)w; w += 3*256*256*2;
  unsigned short* wprojb = (unsigned short*)w; w += 256*256*2;
  unsigned short* xt  = (unsigned short*)w; w += (size_t)4*NSP*256*2;
  unsigned short* q_t = (unsigned short*)w; w += (size_t)4*8*NSP*32*2;
  unsigned short* k_t = (unsigned short*)w; w += (size_t)4*8*NSP*32*2;
  unsigned short* v_b = (unsigned short*)w; w += (size_t)4*256*NSP*2;
  unsigned short* o_part0 = (unsigned short*)w; w += (size_t)4*NSP*256*2;
  unsigned short* o_part1 = (unsigned short*)w; w += (size_t)4*NSP*256*2;
  float* l_part0 = (float*)w;           w += 4*NSP*4;
  float* l_part1 = (float*)w;           w += 4*NSP*4;
  // total ~31.9 MB

  (void)hipMemsetAsync(h1p, 0, (size_t)4*2500*128*2, stream);  // zero pad ring
  k0b_wcast<<<1600, 256, 0, stream>>>(c2w, wq, wk, wv, wproj, wtb, wqkvb, wprojb);
  k0xt    <<<dim3(36,4,4), 256, 0, stream>>>(x, xt);
  k1_luma <<<4, 256, 0, stream>>>(rgb, alphaP, luma_n, bias_a, hm_sum);
  k2_conv1<<<dim3(9,4,4), 256, 0, stream>>>(luma_n, c1w, c1b, h1p);
  k3_conv2<<<dim3(48,2,4), 256, 0, stream>>>(h1p, wtb, c2b, hm_sum);
  k4_film <<<24, 256, 0, stream>>>(hm_sum, gq_w, gq_b, bqf_w, bqf_b,
                                   gk_w, gk_b, bkf_w, bkf_b,
                                   gv_w, gv_b, bvf_w, bvf_b, film);
  k5_qkv  <<<dim3(36,6,4), 256, 0, stream>>>(xt, wqkvb, bq, bk, bv, film,
                                             q_t, k_t, v_b);
  k6_attn <<<dim3(36,8,4), 256, 0, stream>>>(q_t, k_t, v_b, bias_a,
                                             o_part0, o_part1, l_part0, l_part1);
  k7_proj <<<dim3(72,2,4), 256, 0, stream>>>(o_part0, o_part1, l_part0, l_part1,
                                             wprojb, bproj, (float*)d_out);
}

// Round 8
// 302.379 us; speedup vs baseline: 1.1074x; 1.1074x over previous
//
#include <hip/hip_runtime.h>

// ---------------------------------------------------------------------------
// LuminanceAwareMHSA: B=4, C=256, H=W=48 (N=2304), HEADS=8, DH=32, HID=128
// Round 8: k6 PV reverted to K=32 MFMA + per-wave LDS scratch (round-6 path;
// round-7 showed K=16 MFMA costs the same ~4.8cyc as K=32 -> half throughput),
// and split-K raised 2->4 (2304 blocks = 9/CU -> ~32 waves/CU) to attack the
// real limiter: latency at 31% occupancy. k7 chains 4 partial buffers through
// the MFMA C-operand. k1/k4 wave-reduction/coalescing kept from round 7.
//   k0b  cast all weights to bf16;  k0xt transpose x -> xt[b][n][c] bf16
//   K1   luma + min/max norm + pooled-invL bias (pre-scaled alpha*log2e)
//   K2   conv1 3x3 (1->128) + relu -> bf16 padded h1p
//   K3   conv2 via mfma + relu + column-sum -> hm_sum atomics
//   K4   FiLM params (coalesced GEMV)
//   K5   QKV via MFMA + FiLM epilogue -> bf16 q_t/k_t [B,H,N,32], v [B,256,N]
//   K6   flash attention (split-K=4, per-wave LDS) -> bf16 O partials [B,N,256]
//   K7   projection via MFMA, 4-way split-combine through MFMA C chain -> d_out
// ---------------------------------------------------------------------------

#define NSP 2304
#define WID 48

typedef __attribute__((ext_vector_type(4))) float  fvec4;
typedef __attribute__((ext_vector_type(2))) unsigned int uvec2;
typedef __attribute__((ext_vector_type(4))) unsigned int uvec4;
typedef __attribute__((ext_vector_type(8))) short  short8;   // 8 bf16 (4 VGPRs)
typedef __attribute__((ext_vector_type(4))) float  f32x4;    // MFMA C/D

__device__ inline unsigned short f2bf(float f){
  unsigned int u = __builtin_bit_cast(unsigned int, f);
  u += 0x7fffu + ((u >> 16) & 1u);           // RNE
  return (unsigned short)(u >> 16);
}
__device__ inline unsigned pack2bf(float a, float b){
#if __has_builtin(__builtin_amdgcn_cvt_pk_bf16_f32)
  typedef __attribute__((ext_vector_type(2))) __bf16 bf16x2;
  bf16x2 r = __builtin_amdgcn_cvt_pk_bf16_f32(a, b);
  return __builtin_bit_cast(unsigned, r);
#else
  return (unsigned)f2bf(a) | ((unsigned)f2bf(b) << 16);
#endif
}

// ---------------------------------------------------------------------------
// k0b: cast weights to bf16. grid 1600 x 256.
__global__ void k0b_wcast(const float* __restrict__ c2w, const float* __restrict__ wq,
                          const float* __restrict__ wk, const float* __restrict__ wv_,
                          const float* __restrict__ wproj,
                          unsigned short* __restrict__ wtb,
                          unsigned short* __restrict__ wqkvb,
                          unsigned short* __restrict__ wprojb){
  int idx = blockIdx.x*256 + threadIdx.x;
  if (idx < 147456){
    int ic = idx & 127, rem = idx >> 7;
    int oc = rem & 127, tap = rem >> 7;
    wtb[idx] = f2bf(c2w[(oc*128 + ic)*9 + tap]);
  } else if (idx < 344064){
    int j = idx - 147456;
    int mat = j >> 16, oc_ = j & 65535;
    const float* src = (mat == 0) ? wq : (mat == 1) ? wk : wv_;
    wqkvb[j] = f2bf(src[oc_]);
  } else {
    int j = idx - 344064;
    wprojb[j] = f2bf(wproj[j]);
  }
}

// ---------------------------------------------------------------------------
// k0xt: xt[b][n][c] = bf16(x[b][c][n]). grid (36 nt, 4 cc, 4 b).
__global__ __launch_bounds__(256) void k0xt(const float* __restrict__ x,
                                            unsigned short* __restrict__ xt){
  int nt = blockIdx.x, cc = blockIdx.y, b = blockIdx.z, t = threadIdx.x;
  __shared__ unsigned short tb[64*72];
  int cl0 = t >> 4;
  int nl0 = (t & 15) * 4;
  #pragma unroll
  for (int ps = 0; ps < 4; ++ps){
    int cl = cl0 + ps*16;
    fvec4 v = *(const fvec4*)(x + ((size_t)(b*256 + cc*64 + cl))*NSP + nt*64 + nl0);
    #pragma unroll
    for (int i = 0; i < 4; ++i) tb[(nl0+i)*72 + cl] = f2bf(v[i]);
  }
  __syncthreads();
  int nl = t >> 2, cg = (t & 3) * 16;
  uvec4 u0 = *(const uvec4*)&tb[nl*72 + cg];
  uvec4 u1 = *(const uvec4*)&tb[nl*72 + cg + 8];
  unsigned short* dst = xt + ((size_t)(b*NSP + nt*64 + nl))*256 + cc*64 + cg;
  *(uvec4*)dst = u0;
  *(uvec4*)(dst + 8) = u1;
}

// ---------------------------------------------------------------------------
// K1: luma -> minmax-normalize; pooled-invL bias; wave-shfl reductions.
__global__ void k1_luma(const float* __restrict__ rgb, const float* __restrict__ alphaP,
                        float* __restrict__ luma_n, float* __restrict__ bias_a,
                        float* __restrict__ hm_sum){
  int b = blockIdx.x, t = threadIdx.x;
  int wv = t >> 6, lane = t & 63;
  __shared__ float ll[NSP];
  __shared__ float red[8];
  const float* rp = rgb + b*3*NSP;
  float ly[9];
  float lmin = 1e30f, lmax = -1e30f;
  #pragma unroll
  for (int ii = 0; ii < 9; ++ii){
    int i = t + 256*ii;
    float y = 0.299f*rp[i] + 0.587f*rp[NSP+i] + 0.114f*rp[2*NSP+i];
    ly[ii] = y; lmin = fminf(lmin, y); lmax = fmaxf(lmax, y);
  }
  #pragma unroll
  for (int o2 = 1; o2 < 64; o2 <<= 1){
    lmin = fminf(lmin, __shfl_xor(lmin, o2, 64));
    lmax = fmaxf(lmax, __shfl_xor(lmax, o2, 64));
  }
  if (lane == 0){ red[wv] = lmin; red[4+wv] = lmax; }
  if (t < 128) hm_sum[b*128 + t] = 0.f;
  __syncthreads();
  float mn = fminf(fminf(red[0], red[1]), fminf(red[2], red[3]));
  float mx = fmaxf(fmaxf(red[4], red[5]), fmaxf(red[6], red[7]));
  float inv = 1.0f / (mx - mn + 1e-6f);
  #pragma unroll
  for (int ii = 0; ii < 9; ++ii){
    int i = t + 256*ii;
    float v = (ly[ii] - mn) * inv;
    ll[i] = v;
    luma_n[b*NSP + i] = v;
  }
  __syncthreads();
  float pr[9]; float psum = 0.f;
  #pragma unroll
  for (int ii = 0; ii < 9; ++ii){
    int n = t + 256*ii;
    int row = n / WID, col = n - row*WID;
    float s = 0.f;
    #pragma unroll
    for (int dy = -1; dy <= 1; ++dy)
      #pragma unroll
      for (int dx = -1; dx <= 1; ++dx){
        int r2 = row+dy, c2 = col+dx;
        if (r2 >= 0 && r2 < WID && c2 >= 0 && c2 < WID) s += 1.0f - ll[r2*WID + c2];
      }
    pr[ii] = s * (1.f/9.f);
    psum += pr[ii];
  }
  #pragma unroll
  for (int o2 = 1; o2 < 64; o2 <<= 1) psum += __shfl_xor(psum, o2, 64);
  if (lane == 0) red[wv] = psum;
  __syncthreads();
  float mean = (red[0] + red[1] + red[2] + red[3]) * (1.f/(float)NSP);
  float alpha = alphaP[0] * 1.4426950408889634f;   // fold log2(e) for exp2
  #pragma unroll
  for (int ii = 0; ii < 9; ++ii){
    int n = t + 256*ii;
    bias_a[b*NSP + n] = alpha * (pr[ii] - mean);
  }
}

// ---------------------------------------------------------------------------
// K2: conv1 3x3, 1 -> 128 channels, relu -> bf16 padded h1p[b][50*50][128].
__global__ void k2_conv1(const float* __restrict__ luma_n, const float* __restrict__ c1w,
                         const float* __restrict__ c1b, unsigned short* __restrict__ h1p){
  int nt = blockIdx.x, ocg = blockIdx.y, b = blockIdx.z, t = threadIdx.x;
  __shared__ float wsm[32*9];
  __shared__ float bsm[32];
  for (int i = t; i < 288; i += 256) wsm[i] = c1w[ocg*288 + i];
  if (t < 32) bsm[t] = c1b[ocg*32 + t];
  __syncthreads();
  int n = nt*256 + t;
  int row = n / WID, col = n - row*WID;
  const float* lp = luma_n + b*NSP;
  float lv[9];
  int k = 0;
  #pragma unroll
  for (int dy = -1; dy <= 1; ++dy)
    #pragma unroll
    for (int dx = -1; dx <= 1; ++dx, ++k){
      int r2 = row+dy, c2 = col+dx;
      lv[k] = (r2 >= 0 && r2 < WID && c2 >= 0 && c2 < WID) ? lp[r2*WID + c2] : 0.f;
    }
  unsigned int packed[16];
  #pragma unroll
  for (int oc2 = 0; oc2 < 16; ++oc2){
    float a0 = bsm[oc2*2], a1 = bsm[oc2*2+1];
    #pragma unroll
    for (int q = 0; q < 9; ++q){
      a0 += wsm[(oc2*2)*9 + q] * lv[q];
      a1 += wsm[(oc2*2+1)*9 + q] * lv[q];
    }
    packed[oc2] = pack2bf(fmaxf(a0, 0.f), fmaxf(a1, 0.f));
  }
  unsigned short* dst = h1p + ((size_t)(b*2500 + (row+1)*50 + (col+1)))*128 + ocg*32;
  #pragma unroll
  for (int q4 = 0; q4 < 4; ++q4)
    *(uvec4*)(dst + q4*8) = *(uvec4*)&packed[q4*4];
}

// ---------------------------------------------------------------------------
// K3: conv2 128->128 as 9 shifted MFMA GEMMs + relu + column-sum -> hm_sum.
__global__ __launch_bounds__(256) void k3_conv2(const unsigned short* __restrict__ h1p,
    const unsigned short* __restrict__ wtb, const float* __restrict__ c2b,
    float* __restrict__ hm_sum){
  int row = blockIdx.x, mh = blockIdx.y, b = blockIdx.z;
  int t = threadIdx.x, wv = t >> 6, lane = t & 63;
  int lq = lane >> 4, lc = lane & 15;
  int ocb = mh*64 + wv*16;
  const f32x4 z4 = {0.f, 0.f, 0.f, 0.f};
  f32x4 C[3] = {z4, z4, z4};
  const unsigned short* hbase = h1p + (size_t)b*2500*128;
  #pragma unroll
  for (int tap = 0; tap < 9; ++tap){
    int dy = tap/3 - 1, dx = tap%3 - 1;
    const unsigned short* wrow = wtb + (tap*128 + ocb + lc)*128 + lq*8;
    const unsigned short* hrow = hbase + ((row+dy+1)*50 + (dx+1) + lc)*128 + lq*8;
    #pragma unroll
    for (int kc = 0; kc < 4; ++kc){
      short8 aW = *(const short8*)(wrow + kc*32);
      #pragma unroll
      for (int ntp = 0; ntp < 3; ++ntp){
        short8 bH = *(const short8*)(hrow + ntp*16*128 + kc*32);
        C[ntp] = __builtin_amdgcn_mfma_f32_16x16x32_bf16(aW, bH, C[ntp], 0, 0, 0);
      }
    }
  }
  float s[4];
  #pragma unroll
  for (int r = 0; r < 4; ++r){
    float bias = c2b[ocb + lq*4 + r];
    float v = 0.f;
    #pragma unroll
    for (int ntp = 0; ntp < 3; ++ntp) v += fmaxf(C[ntp][r] + bias, 0.f);
    v += __shfl_xor(v, 1, 64);
    v += __shfl_xor(v, 2, 64);
    v += __shfl_xor(v, 4, 64);
    v += __shfl_xor(v, 8, 64);
    s[r] = v;
  }
  if (lc == 0){
    #pragma unroll
    for (int r = 0; r < 4; ++r)
      atomicAdd(&hm_sum[b*128 + ocb + lq*4 + r], s[r]);
  }
}

// ---------------------------------------------------------------------------
// K4: FiLM params, coalesced GEMV. film[(m6*4+b)*256 + o].
__global__ void k4_film(const float* __restrict__ hm_sum,
  const float* w0, const float* b0, const float* w1, const float* b1,
  const float* w2, const float* b2, const float* w3, const float* b3,
  const float* w4, const float* b4, const float* w5, const float* b5,
  float* __restrict__ film){
  __shared__ float hs[128];
  int bb = blockIdx.x & 3, m6 = blockIdx.x >> 2, t = threadIdx.x;
  if (t < 128) hs[t] = hm_sum[bb*128 + t] * (1.f/(float)NSP);
  __syncthreads();
  const float* wm[6] = {w0,w1,w2,w3,w4,w5};
  const float* bm[6] = {b0,b1,b2,b3,b4,b5};
  const float* w = wm[m6];
  const float* bv6 = bm[m6];
  int oi = t >> 3, hi = t & 7;
  float hreg[16];
  #pragma unroll
  for (int q = 0; q < 16; ++q) hreg[q] = hs[hi*16 + q];
  #pragma unroll
  for (int pass = 0; pass < 8; ++pass){
    int o = pass*32 + oi;
    const float* wr = w + o*128 + hi*16;
    float p = 0.f;
    #pragma unroll
    for (int q4 = 0; q4 < 4; ++q4){
      fvec4 w4v = *(const fvec4*)(wr + q4*4);
      p += hreg[q4*4+0]*w4v[0] + hreg[q4*4+1]*w4v[1]
         + hreg[q4*4+2]*w4v[2] + hreg[q4*4+3]*w4v[3];
    }
    p += __shfl_xor(p, 1, 64);
    p += __shfl_xor(p, 2, 64);
    p += __shfl_xor(p, 4, 64);
    if (hi == 0) film[blockIdx.x*256 + o] = p + bv6[o];
  }
}

// ---------------------------------------------------------------------------
// K5: QKV via bf16 MFMA. grid (36 nt, 6 ot, 4 b); FiLM epilogue; emits
// q_t/k_t [B,8,N,32] bf16 (SCALE*log2e in q), v_b [B,256,N] bf16.
__global__ __launch_bounds__(256) void k5_qkv(const unsigned short* __restrict__ xt,
    const unsigned short* __restrict__ wqkvb,
    const float* __restrict__ bq, const float* __restrict__ bk, const float* __restrict__ bv,
    const float* __restrict__ film,
    unsigned short* __restrict__ q_t, unsigned short* __restrict__ k_t,
    unsigned short* __restrict__ v_b){
  int nt = blockIdx.x, ot = blockIdx.y, b = blockIdx.z;
  int t = threadIdx.x, wv = t >> 6, lane = t & 63;
  int lq = lane >> 4, lc = lane & 15;
  int p = ot >> 1;
  int omb = (ot & 1)*128 + wv*32;
  const unsigned short* wb = wqkvb + p*65536;
  const f32x4 z4 = {0.f, 0.f, 0.f, 0.f};
  f32x4 acc[2][4];
  #pragma unroll
  for (int oh = 0; oh < 2; ++oh)
    #pragma unroll
    for (int nq = 0; nq < 4; ++nq) acc[oh][nq] = z4;
  for (int kc = 0; kc < 8; ++kc){
    short8 aW[2];
    #pragma unroll
    for (int oh = 0; oh < 2; ++oh)
      aW[oh] = *(const short8*)(wb + (omb + oh*16 + lc)*256 + kc*32 + lq*8);
    short8 bX[4];
    #pragma unroll
    for (int nq = 0; nq < 4; ++nq)
      bX[nq] = *(const short8*)(xt + ((size_t)(b*NSP + nt*64 + nq*16 + lc))*256 + kc*32 + lq*8);
    #pragma unroll
    for (int oh = 0; oh < 2; ++oh)
      #pragma unroll
      for (int nq = 0; nq < 4; ++nq)
        acc[oh][nq] = __builtin_amdgcn_mfma_f32_16x16x32_bf16(aW[oh], bX[nq], acc[oh][nq], 0, 0, 0);
  }
  const float* bvec = (p == 0) ? bq : (p == 1) ? bk : bv;
  int hq = omb >> 5;
  unsigned short* qk = (p == 0) ? q_t : k_t;
  #pragma unroll
  for (int oh = 0; oh < 2; ++oh){
    fvec4 g4 = *(const fvec4*)(film + (2*p*4 + b)*256 + omb + oh*16 + lq*4);
    fvec4 t4 = *(const fvec4*)(film + ((2*p+1)*4 + b)*256 + omb + oh*16 + lq*4);
    fvec4 z4b = *(const fvec4*)(bvec + omb + oh*16 + lq*4);
    #pragma unroll
    for (int nq = 0; nq < 4; ++nq){
      int n = nt*64 + nq*16 + lc;
      float v0 = g4[0]*(acc[oh][nq][0] + z4b[0]) + t4[0];
      float v1 = g4[1]*(acc[oh][nq][1] + z4b[1]) + t4[1];
      float v2 = g4[2]*(acc[oh][nq][2] + z4b[2]) + t4[2];
      float v3 = g4[3]*(acc[oh][nq][3] + z4b[3]) + t4[3];
      if (p == 0){
        const float sc = 0.17677669529663687f * 1.4426950408889634f;  // SCALE*log2e
        v0 *= sc; v1 *= sc; v2 *= sc; v3 *= sc;
      }
      if (p < 2){
        uvec2 u;
        u.x = pack2bf(v0, v1);
        u.y = pack2bf(v2, v3);
        *(uvec2*)(qk + ((size_t)((b*8 + hq)*NSP + n))*32 + oh*16 + lq*4) = u;
      } else {
        int om = omb + oh*16 + lq*4;
        v_b[((size_t)(b*256 + om + 0))*NSP + n] = f2bf(v0);
        v_b[((size_t)(b*256 + om + 1))*NSP + n] = f2bf(v1);
        v_b[((size_t)(b*256 + om + 2))*NSP + n] = f2bf(v2);
        v_b[((size_t)(b*256 + om + 3))*NSP + n] = f2bf(v3);
      }
    }
  }
}

// ---------------------------------------------------------------------------
// K6: flash attention, split-K=4 (9 key-tiles per block), barrier-free.
// S^T = mfma_16x16x32(A=K, B=Q^T, C=bias): D[key=lq*4+r][query=lc].
// P^T -> PV B-layout via per-wave LDS scratch (xor-swizzled packed bf16);
// PV + l via K=32 MFMA (K=16 variant measured same cyc/instr -> avoid).
// Stores bf16 O partials [B,N,256] + f32 l. grid (72 = 18 qblk x 4 split, 8, 4).
__global__ __launch_bounds__(256) void k6_attn(const unsigned short* __restrict__ q_t,
    const unsigned short* __restrict__ k_t, const unsigned short* __restrict__ v_b,
    const float* __restrict__ bias_a,
    unsigned short* __restrict__ o0, unsigned short* __restrict__ o1,
    unsigned short* __restrict__ o2, unsigned short* __restrict__ o3,
    float* __restrict__ l0, float* __restrict__ l1,
    float* __restrict__ l2, float* __restrict__ l3){
  int bx = blockIdx.x, h = blockIdx.y, b = blockIdx.z;
  int qblk = bx >> 2, s = bx & 3;
  unsigned short* op = (s == 0) ? o0 : (s == 1) ? o1 : (s == 2) ? o2 : o3;
  float* lp = (s == 0) ? l0 : (s == 1) ? l1 : (s == 2) ? l2 : l3;
  int t = threadIdx.x, wv = t >> 6, lane = t & 63;
  int lq = lane >> 4, lc = lane & 15;
  int bh = b*8 + h;
  int nb0 = qblk*128 + wv*32;
  const f32x4 z4 = {0.f, 0.f, 0.f, 0.f};
  __shared__ float ps[4][512];        // per-wave P scratch (2 KB each)
  float* myps = ps[wv];
  int xm = (lc & 7) << 2;             // xor swizzle mask (dwords)
  int wbase = lc*32;                  // per-query row base (dwords)
  const uvec4 onesu = {0x3F803F80u, 0x3F803F80u, 0x3F803F80u, 0x3F803F80u};
  const short8 aOnes = __builtin_bit_cast(short8, onesu);
  short8 aQ[2];
  #pragma unroll
  for (int qf = 0; qf < 2; ++qf)
    aQ[qf] = *(const short8*)(q_t + ((size_t)(bh*NSP + nb0 + qf*16 + lc))*32 + lq*8);
  f32x4 O[2][2];
  f32x4 Ol[2];
  #pragma unroll
  for (int qf = 0; qf < 2; ++qf){
    Ol[qf] = z4;
    #pragma unroll
    for (int dh = 0; dh < 2; ++dh) O[qf][dh] = z4;
  }
  const float* brow = bias_a + b*NSP;
  int ms = s*576;

  for (int it = 0; it < 9; ++it){
    int m0 = ms + it*64;
    short8 aK[4]; fvec4 c0[4]; short8 aV[2][2];
    #pragma unroll
    for (int g = 0; g < 4; ++g)
      aK[g] = *(const short8*)(k_t + ((size_t)(bh*NSP + m0 + g*16 + lc))*32 + lq*8);
    #pragma unroll
    for (int g = 0; g < 4; ++g)
      c0[g] = *(const fvec4*)(brow + m0 + g*16 + lq*4);
    #pragma unroll
    for (int dh = 0; dh < 2; ++dh)
      #pragma unroll
      for (int mh = 0; mh < 2; ++mh)
        aV[dh][mh] = *(const short8*)(v_b + ((size_t)(b*256 + h*32 + dh*16 + lc))*NSP + m0 + mh*32 + lq*8);
    #pragma unroll
    for (int qf = 0; qf < 2; ++qf){
      #pragma unroll
      for (int g = 0; g < 4; ++g){
        f32x4 S = __builtin_amdgcn_mfma_f32_16x16x32_bf16(aK[g], aQ[qf], c0[g], 0, 0, 0);
        uvec2 w2;
        w2.x = pack2bf(__builtin_amdgcn_exp2f(S[0]), __builtin_amdgcn_exp2f(S[1]));
        w2.y = pack2bf(__builtin_amdgcn_exp2f(S[2]), __builtin_amdgcn_exp2f(S[3]));
        int kp = g*8 + lq*2;
        *(uvec2*)&myps[wbase + (kp ^ xm)] = w2;
      }
      #pragma unroll
      for (int mh = 0; mh < 2; ++mh){
        int rb = (mh*16 + lq*4) ^ xm;
        uvec4 up = *(const uvec4*)&myps[wbase + rb];
        short8 bP = __builtin_bit_cast(short8, up);
        Ol[qf] = __builtin_amdgcn_mfma_f32_16x16x32_bf16(aOnes, bP, Ol[qf], 0, 0, 0);
        #pragma unroll
        for (int dh = 0; dh < 2; ++dh)
          O[qf][dh] = __builtin_amdgcn_mfma_f32_16x16x32_bf16(aV[dh][mh], bP, O[qf][dh], 0, 0, 0);
      }
    }
  }
  // store bf16 O partials [b][n][og] (og = h*32 + d), f32 l partials
  #pragma unroll
  for (int qf = 0; qf < 2; ++qf){
    int nidx = nb0 + qf*16 + lc;
    if (lq == 0) lp[b*NSP + nidx] = Ol[qf][0];
    #pragma unroll
    for (int dh = 0; dh < 2; ++dh){
      uvec2 u;
      u.x = pack2bf(O[qf][dh][0], O[qf][dh][1]);
      u.y = pack2bf(O[qf][dh][2], O[qf][dh][3]);
      *(uvec2*)(op + ((size_t)(b*NSP + nidx))*256 + h*32 + dh*16 + lq*4) = u;
    }
  }
}

// ---------------------------------------------------------------------------
// K7: out[c][n] = (sum_o wproj[c][o]*(a0+a1+a2+a3)[o][n]) * rl[n] + bproj[c].
// bf16 MFMA; the 4 split partials combined through the MFMA C chain.
// grid (72 nt(32 n), 2 ct(128 c), 4 b); wave: 32 c x 32 n.
__global__ __launch_bounds__(256) void k7_proj(const unsigned short* __restrict__ a0,
    const unsigned short* __restrict__ a1, const unsigned short* __restrict__ a2,
    const unsigned short* __restrict__ a3,
    const float* __restrict__ l0p, const float* __restrict__ l1p,
    const float* __restrict__ l2p, const float* __restrict__ l3p,
    const unsigned short* __restrict__ wprojb,
    const float* __restrict__ bproj, float* __restrict__ out){
  int nt = blockIdx.x, ct = blockIdx.y, b = blockIdx.z;
  int t = threadIdx.x, wv = t >> 6, lane = t & 63;
  int lq = lane >> 4, lc = lane & 15;
  __shared__ float rls[32];
  if (t < 32){
    int gi = b*NSP + nt*32 + t;
    rls[t] = 1.0f / (l0p[gi] + l1p[gi] + l2p[gi] + l3p[gi]);
  }
  __syncthreads();
  int cb = ct*128 + wv*32;
  const f32x4 z4 = {0.f, 0.f, 0.f, 0.f};
  f32x4 acc[2][2];
  #pragma unroll
  for (int ch = 0; ch < 2; ++ch)
    #pragma unroll
    for (int nq = 0; nq < 2; ++nq) acc[ch][nq] = z4;
  const unsigned short* srcs[4] = {a0, a1, a2, a3};
  for (int kc = 0; kc < 8; ++kc){
    short8 aW[2];
    #pragma unroll
    for (int ch = 0; ch < 2; ++ch)
      aW[ch] = *(const short8*)(wprojb + (cb + ch*16 + lc)*256 + kc*32 + lq*8);
    #pragma unroll
    for (int src = 0; src < 4; ++src){
      const unsigned short* ap = srcs[src];
      short8 bA[2];
      #pragma unroll
      for (int nq = 0; nq < 2; ++nq)
        bA[nq] = *(const short8*)(ap + ((size_t)(b*NSP + nt*32 + nq*16 + lc))*256 + kc*32 + lq*8);
      #pragma unroll
      for (int ch = 0; ch < 2; ++ch)
        #pragma unroll
        for (int nq = 0; nq < 2; ++nq)
          acc[ch][nq] = __builtin_amdgcn_mfma_f32_16x16x32_bf16(aW[ch], bA[nq], acc[ch][nq], 0, 0, 0);
    }
  }
  #pragma unroll
  for (int ch = 0; ch < 2; ++ch){
    #pragma unroll
    for (int nq = 0; nq < 2; ++nq){
      int n = nt*32 + nq*16 + lc;
      float rl = rls[nq*16 + lc];
      #pragma unroll
      for (int r = 0; r < 4; ++r){
        int c = cb + ch*16 + lq*4 + r;
        out[((size_t)(b*256 + c))*NSP + n] = acc[ch][nq][r]*rl + bproj[c];
      }
    }
  }
}

// ---------------------------------------------------------------------------
extern "C" void kernel_launch(void* const* d_in, const int* in_sizes, int n_in,
                              void* d_out, int out_size, void* d_ws, size_t ws_size,
                              hipStream_t stream) {
  const float* x     = (const float*)d_in[0];
  const float* rgb   = (const float*)d_in[1];
  const float* wq    = (const float*)d_in[2];
  const float* bq    = (const float*)d_in[3];
  const float* wk    = (const float*)d_in[4];
  const float* bk    = (const float*)d_in[5];
  const float* wv    = (const float*)d_in[6];
  const float* bv    = (const float*)d_in[7];
  const float* wproj = (const float*)d_in[8];
  const float* bproj = (const float*)d_in[9];
  const float* c1w   = (const float*)d_in[10];
  const float* c1b   = (const float*)d_in[11];
  const float* c2w   = (const float*)d_in[12];
  const float* c2b   = (const float*)d_in[13];
  const float* gq_w  = (const float*)d_in[14];
  const float* gq_b  = (const float*)d_in[15];
  const float* bqf_w = (const float*)d_in[16];
  const float* bqf_b = (const float*)d_in[17];
  const float* gk_w  = (const float*)d_in[18];
  const float* gk_b  = (const float*)d_in[19];
  const float* bkf_w = (const float*)d_in[20];
  const float* bkf_b = (const float*)d_in[21];
  const float* gv_w  = (const float*)d_in[22];
  const float* gv_b  = (const float*)d_in[23];
  const float* bvf_w = (const float*)d_in[24];
  const float* bvf_b = (const float*)d_in[25];
  const float* alphaP= (const float*)d_in[26];

  char* w = (char*)d_ws;
  float* luma_n = (float*)w;            w += 4*NSP*4;
  float* bias_a = (float*)w;            w += 4*NSP*4;
  float* hm_sum = (float*)w;            w += 512*4;
  float* film   = (float*)w;            w += 6*4*256*4;
  unsigned short* h1p = (unsigned short*)w; w += 4*2500*128*2;
  unsigned short* wtb = (unsigned short*)w; w += 9*128*128*2;
  unsigned short* wqkvb = (unsigned short*)w; w += 3*256*256*2;
  unsigned short* wprojb = (unsigned short*)w; w += 256*256*2;
  unsigned short* xt  = (unsigned short*)w; w += (size_t)4*NSP*256*2;
  unsigned short* q_t = (unsigned short*)w; w += (size_t)4*8*NSP*32*2;
  unsigned short* k_t = (unsigned short*)w; w += (size_t)4*8*NSP*32*2;
  unsigned short* v_b = (unsigned short*)w; w += (size_t)4*256*NSP*2;
  unsigned short* o_part[4];
  for (int i = 0; i < 4; ++i){ o_part[i] = (unsigned short*)w; w += (size_t)4*NSP*256*2; }
  float* l_part[4];
  for (int i = 0; i < 4; ++i){ l_part[i] = (float*)w; w += 4*NSP*4; }
  // total ~41.5 MB

  (void)hipMemsetAsync(h1p, 0, (size_t)4*2500*128*2, stream);  // zero pad ring
  k0b_wcast<<<1600, 256, 0, stream>>>(c2w, wq, wk, wv, wproj, wtb, wqkvb, wprojb);
  k0xt    <<<dim3(36,4,4), 256, 0, stream>>>(x, xt);
  k1_luma <<<4, 256, 0, stream>>>(rgb, alphaP, luma_n, bias_a, hm_sum);
  k2_conv1<<<dim3(9,4,4), 256, 0, stream>>>(luma_n, c1w, c1b, h1p);
  k3_conv2<<<dim3(48,2,4), 256, 0, stream>>>(h1p, wtb, c2b, hm_sum);
  k4_film <<<24, 256, 0, stream>>>(hm_sum, gq_w, gq_b, bqf_w, bqf_b,
                                   gk_w, gk_b, bkf_w, bkf_b,
                                   gv_w, gv_b, bvf_w, bvf_b, film);
  k5_qkv  <<<dim3(36,6,4), 256, 0, stream>>>(xt, wqkvb, bq, bk, bv, film,
                                             q_t, k_t, v_b);
  k6_attn <<<dim3(72,8,4), 256, 0, stream>>>(q_t, k_t, v_b, bias_a,
                                             o_part[0], o_part[1], o_part[2], o_part[3],
                                             l_part[0], l_part[1], l_part[2], l_part[3]);
  k7_proj <<<dim3(72,2,4), 256, 0, stream>>>(o_part[0], o_part[1], o_part[2], o_part[3],
                                             l_part[0], l_part[1], l_part[2], l_part[3],
                                             wprojb, bproj, (float*)d_out);
}